// Round 8
// baseline (129.983 us; speedup 1.0000x reference)
//
#include <hip/hip_runtime.h>

// Problem constants (from reference setup_inputs).
#define BATCH 4
#define NQ    8192
#define NA    6890
#define NT    216              // anchor tiles of 32
#define NAPAD (NT*32)          // 6912
#define KS    32               // k-slots per row (two 32x32x16 MFMAs)
#define QT    64               // queries per block (two 32-query MFMA groups)
#define WPB   8                // waves per block
#define TPW   27               // anchor tiles per wave (216/8)

typedef __attribute__((ext_vector_type(8)))  short bf16x8;
typedef __attribute__((ext_vector_type(16))) float f32x16;

#define A_ROWS (BATCH*NQ)      // 32768
#define B_ROWS (BATCH*NAPAD)   // 27648
#define A_BYTES ((size_t)A_ROWS*KS*2)   // 2 MB

__device__ __forceinline__ unsigned short f2bf(float x) {   // RNE fp32->bf16
    unsigned b = __float_as_uint(x);
    b += 0x7FFFu + ((b >> 16) & 1u);
    return (unsigned short)(b >> 16);
}
__device__ __forceinline__ float bf2f(unsigned short u) {
    return __uint_as_float(((unsigned)u) << 16);
}
// 3-term bf16 split: x = h + m + l + O(2^-27 x)
__device__ __forceinline__ void split3(float x, unsigned short o[3]) {
    const unsigned short h = f2bf(x); const float fh = bf2f(h);
    const float r1 = x - fh;
    const unsigned short m = f2bf(r1); const float fm = bf2f(m);
    o[0] = h; o[1] = m; o[2] = f2bf(r1 - fm);
}

// k-slot term table: slot = d*8+p. Pair p -> (q-term, a-term), h=0 m=1 l=2.
// Kept pairs: hh,hm,mh,hl,mm,lh,ml,lm (drop ll ~ 2^-27).
__constant__ int QT_OF[8] = {0,0,1,0,1,2,1,2};
__constant__ int AT_OF[8] = {0,1,0,2,1,0,2,1};

// Build A_ext[b][q][32] (negated q terms + 1.0s + q^2/2 splits) and
// B_ext[b][a][32] (a terms + |a|^2/2 splits + 1.0s); zero d_out.
// acc = sum_k A*B = q^2/2 + |a|^2/2 - q.a = d^2/2 >= 0.   (verified absmax 0)
__global__ void precompute_kernel(const float* __restrict__ query,
                                  const float* __restrict__ anchor,
                                  unsigned short* __restrict__ Aext,
                                  unsigned short* __restrict__ Bext,
                                  float* __restrict__ out) {
    const int i = blockIdx.x * blockDim.x + threadIdx.x;
    if (i < BATCH) out[i] = 0.0f;              // d_out poisoned each call
    unsigned short s[KS];
    #pragma unroll
    for (int k = 0; k < KS; ++k) s[k] = 0;

    if (i < A_ROWS) {                          // one query row
        const float* qp = query + (size_t)i * 3;
        const float qx = qp[0], qy = qp[1], qz = qp[2];
        unsigned short sp[3][3];
        split3(qx, sp[0]); split3(qy, sp[1]); split3(qz, sp[2]);
        #pragma unroll
        for (int d = 0; d < 3; ++d)
            #pragma unroll
            for (int p = 0; p < 8; ++p)
                s[d*8+p] = sp[d][QT_OF[p]] ^ 0x8000;   // negate: -q terms
        s[24] = s[25] = s[26] = 0x3F80;                // 1.0 (pairs |a|^2/2)
        unsigned short q2s[3];
        split3(0.5f * (qx*qx + qy*qy + qz*qz), q2s);
        s[27] = q2s[0]; s[28] = q2s[1]; s[29] = q2s[2];
        uint4* dst = (uint4*)(Aext + (size_t)i * KS);
        const uint4* sv = (const uint4*)s;
        dst[0]=sv[0]; dst[1]=sv[1]; dst[2]=sv[2]; dst[3]=sv[3];
    } else if (i < A_ROWS + B_ROWS) {          // one anchor row
        const int j = i - A_ROWS;
        const int b = j / NAPAD, k = j - b * NAPAD;
        if (k < NA) {
            const float* ap = anchor + ((size_t)b * NA + k) * 3;
            const float ax = ap[0], ay = ap[1], az = ap[2];
            unsigned short sp[3][3];
            split3(ax, sp[0]); split3(ay, sp[1]); split3(az, sp[2]);
            #pragma unroll
            for (int d = 0; d < 3; ++d)
                #pragma unroll
                for (int p = 0; p < 8; ++p)
                    s[d*8+p] = sp[d][AT_OF[p]];
            unsigned short hs[3];
            split3(0.5f * (ax*ax + ay*ay + az*az), hs);
            s[24] = hs[0]; s[25] = hs[1]; s[26] = hs[2];
        } else {
            s[24] = f2bf(1.0e30f);             // pad: score = huge, never wins
        }
        s[27] = s[28] = s[29] = 0x3F80;        // 1.0 (pairs q^2/2)
        uint4* dst = (uint4*)(Bext + (size_t)j * KS);
        const uint4* sv = (const uint4*)s;
        dst[0]=sv[0]; dst[1]=sv[1]; dst[2]=sv[2]; dst[3]=sv[3];
    }
}

// Butterfly min over each 32-lane group via ds_swizzle (BitMode, and=0x1F).
__device__ __forceinline__ unsigned swz_min32(unsigned v) {
    unsigned u;
    u = (unsigned)__builtin_amdgcn_ds_swizzle((int)v, 0x041F); v = (u < v) ? u : v;
    u = (unsigned)__builtin_amdgcn_ds_swizzle((int)v, 0x081F); v = (u < v) ? u : v;
    u = (unsigned)__builtin_amdgcn_ds_swizzle((int)v, 0x101F); v = (u < v) ? u : v;
    u = (unsigned)__builtin_amdgcn_ds_swizzle((int)v, 0x201F); v = (u < v) ? u : v;
    u = (unsigned)__builtin_amdgcn_ds_swizzle((int)v, 0x401F); v = (u < v) ? u : v;
    return v;
}

// One block = 64 queries (two 32x32 MFMA groups); 8 waves split the 216
// anchor tiles (27 each). 32x32x16 bf16 MFMA fragment mapping as verified
// in R7 (absmax 0): A[m=lane&31][k=hi*8+j | 16+hi*8+j]; B same k packing;
// C/D: col=lane&31 (anchor), row=(reg&3)+8*(reg>>2)+4*hi (query) [m74/m101].
__global__ __launch_bounds__(512, 4)
void collision_kernel(const float* __restrict__ query,
                      const float* __restrict__ anchor,
                      const float* __restrict__ normals,
                      const unsigned short* __restrict__ Aext,
                      const unsigned short* __restrict__ Bext,
                      float* __restrict__ out) {
    __shared__ unsigned s_red[WPB][QT];       // 2 KB

    const int lane = threadIdx.x & 63;
    const int wave = threadIdx.x >> 6;
    const int b  = blockIdx.x >> 7;           // batch
    const int qt = blockIdx.x & 127;          // query tile (64 queries)
    const int col = lane & 31;
    const int hi  = lane >> 5;

    // Two A fragments (query groups qt*64+[0,32) and +[32,64)).
    const unsigned short* Abase = Aext + ((size_t)b*NQ + (size_t)qt*QT) * KS;
    const unsigned short* Ar0 = Abase + (size_t)col * KS + hi*8;
    const unsigned short* Ar1 = Abase + (size_t)(32 + col) * KS + hi*8;
    const bf16x8 a00 = *(const bf16x8*)(Ar0);
    const bf16x8 a01 = *(const bf16x8*)(Ar0 + 16);
    const bf16x8 a10 = *(const bf16x8*)(Ar1);
    const bf16x8 a11 = *(const bf16x8*)(Ar1 + 16);

    const f32x16 zero = {0,0,0,0,0,0,0,0,0,0,0,0,0,0,0,0};
    unsigned run0[16], run1[16];
    #pragma unroll
    for (int r = 0; r < 16; ++r) { run0[r] = 0xFFFFFFFFu; run1[r] = 0xFFFFFFFFu; }

    const unsigned short* Bbase = Bext + (size_t)b*NAPAD*KS + hi*8;
    const int t0 = wave * TPW;

    // Distance-1 prefetch pipeline (clamped: last iter reloads current tile).
    const unsigned short* Bc = Bbase + (size_t)(t0*32 + col) * KS;
    bf16x8 c0 = *(const bf16x8*)Bc;
    bf16x8 c1 = *(const bf16x8*)(Bc + 16);

    #pragma unroll 2
    for (int ti = 0; ti < TPW; ++ti) {
        const int t  = t0 + ti;
        const int tn = (ti + 1 < TPW) ? (t + 1) : t;
        const unsigned short* Bn = Bbase + (size_t)(tn*32 + col) * KS;
        const bf16x8 n0 = *(const bf16x8*)Bn;
        const bf16x8 n1 = *(const bf16x8*)(Bn + 16);

        f32x16 acc0 = __builtin_amdgcn_mfma_f32_32x32x16_bf16(a00, c0, zero, 0,0,0);
        acc0        = __builtin_amdgcn_mfma_f32_32x32x16_bf16(a01, c1, acc0, 0,0,0);
        f32x16 acc1 = __builtin_amdgcn_mfma_f32_32x32x16_bf16(a10, c0, zero, 0,0,0);
        acc1        = __builtin_amdgcn_mfma_f32_32x32x16_bf16(a11, c1, acc1, 0,0,0);

        // score=d^2/2>=0: float bits order as uint; pack 13-bit anchor idx.
        const unsigned aidx = (unsigned)(t*32 + col);
        #pragma unroll
        for (int r = 0; r < 16; ++r) {
            const unsigned k0 = (__float_as_uint(acc0[r]) & 0xFFFFE000u) | aidx;
            run0[r] = (k0 < run0[r]) ? k0 : run0[r];
            const unsigned k1 = (__float_as_uint(acc1[r]) & 0xFFFFE000u) | aidx;
            run1[r] = (k1 < run1[r]) ? k1 : run1[r];
        }
        c0 = n0; c1 = n1;
    }

    // Cross-lane argmin within each 32-lane group (keys unique: order-free).
    #pragma unroll
    for (int r = 0; r < 16; ++r) {
        run0[r] = swz_min32(run0[r]);
        run1[r] = swz_min32(run1[r]);
    }
    if (col == 0) {   // lanes 0 and 32 hold their group's minima
        #pragma unroll
        for (int r = 0; r < 16; ++r) {
            const int row = (r & 3) + 8*(r >> 2) + 4*hi;
            s_red[wave][row]      = run0[r];
            s_red[wave][32 + row] = run1[r];
        }
    }
    __syncthreads();

    if (threadIdx.x < QT) {                    // wave 0, all 64 lanes
        const int t = threadIdx.x;             // query row within block
        unsigned bk = s_red[0][t];
        #pragma unroll
        for (int w = 1; w < WPB; ++w) {
            const unsigned v = s_red[w][t];
            bk = (v < bk) ? v : bk;
        }
        const int bidx = (int)(bk & 0x1FFFu);  // < NA (pads can't win)
        const int qq = qt*QT + t;
        const float* qp = query   + ((size_t)b*NQ + qq)   * 3;
        const float* ap = anchor  + ((size_t)b*NA + bidx) * 3;
        const float* np = normals + ((size_t)b*NA + bidx) * 3;
        const float qx = qp[0], qy = qp[1], qz = qp[2];
        const float dx = qx-ap[0], dy = qy-ap[1], dz = qz-ap[2];
        const float d2  = fmaf(dz, dz, fmaf(dy, dy, dx*dx));
        const float dot = fmaf(dz, np[2], fmaf(dy, np[1], dx*np[0]));
        // dot * (l2 <= 0.5) < 0  <=>  dot < 0 && d2 <= 0.25
        const bool coll = (dot < 0.0f) && (d2 <= 0.25f);
        const unsigned long long m = __ballot(coll);
        if (t == 0) atomicAdd(out + b, (float)__popcll(m));
    }
}

extern "C" void kernel_launch(void* const* d_in, const int* in_sizes, int n_in,
                              void* d_out, int out_size, void* d_ws, size_t ws_size,
                              hipStream_t stream) {
    const float* query   = (const float*)d_in[0];
    const float* anchor  = (const float*)d_in[1];
    const float* normals = (const float*)d_in[2];
    float* out = (float*)d_out;
    unsigned short* Aext = (unsigned short*)d_ws;              // 2 MB
    unsigned short* Bext = (unsigned short*)((char*)d_ws + A_BYTES); // 1.73 MB

    const int npre = A_ROWS + B_ROWS;                          // 60416
    precompute_kernel<<<dim3((npre + 255) / 256), dim3(256), 0, stream>>>(
        query, anchor, Aext, Bext, out);

    const int grid = BATCH * (NQ / QT);        // 512 blocks x 512 threads
    collision_kernel<<<dim3(grid), dim3(512), 0, stream>>>(
        query, anchor, normals, Aext, Bext, out);
}